// Round 2
// baseline (274.275 us; speedup 1.0000x reference)
//
#include <hip/hip_runtime.h>

#define HH 1024
#define WW 1024
#define TH 16          // output rows per tile
#define TW 116         // output cols per tile (even -> float2-aligned halo)
#define WL 128         // colsum slots = halo cols C0-6 .. C0+121
#define SSIM_C1 1e-4f
#define SSIM_C2 9e-4f

__global__ void ssim_ws_init(float* ws) { ws[0] = 0.f; }

__global__ __launch_bounds__(256, 5) void ssim_main(const float* __restrict__ img1,
                                                    const float* __restrict__ img2,
                                                    const float* __restrict__ window,
                                                    float* __restrict__ ws)
{
    __shared__ float4 cs4[TH][WL];   // 32 KB: colsums {s1,s2,(x+y)^2,(x-y)^2}

    const int tx = blockIdx.x;       // col tile: 0..8
    const int ty = blockIdx.y;       // row tile: 0..63
    const int b  = blockIdx.z;       // batch
    const int C0 = tx * TW;
    const int R0 = ty * TH;
    const int t  = threadIdx.x;
    const size_t ibase = (size_t)b * (size_t)(HH * WW);

    // ---- Phase 1: vertical 11-row sums. 64 col-pair threads x 4 row-chunks.
    // Chunk q produces colsum rows 4q..4q+3 from image rows R0-5+4q .. R0+8+4q
    // via running prefix + 3 snapshots (out[i] = P[i+10] - P[i-1]).
    {
        const int cg = t & 63;           // column pair: slots 2cg, 2cg+1
        const int q  = t >> 6;           // row chunk 0..3 (one wave each)
        const int gc = C0 - 6 + 2 * cg;  // even -> 8B-aligned float2
        const bool cok = (unsigned)gc < (unsigned)WW;
        const float2* p1 = (const float2*)(img1 + ibase + gc);
        const float2* p2 = (const float2*)(img2 + ibase + gc);
        const int jbase = R0 - 5 + 4 * q;

        float s1a=0.f,s2a=0.f,spa=0.f,sqa=0.f;
        float s1b=0.f,s2b=0.f,spb=0.f,sqb=0.f;
        float sn[3][8];
#pragma unroll
        for (int k = 0; k < 14; ++k) {
            const int j = jbase + k;
            float2 x = make_float2(0.f, 0.f), y = make_float2(0.f, 0.f);
            if (cok && (unsigned)j < (unsigned)HH) {
                const size_t off = (size_t)j * (WW / 2);
                x = p1[off];
                y = p2[off];
            }
            { const float aa = x.x + y.x, dd = x.x - y.x;
              s1a += x.x; s2a += y.x; spa += aa * aa; sqa += dd * dd; }
            { const float aa = x.y + y.y, dd = x.y - y.y;
              s1b += x.y; s2b += y.y; spb += aa * aa; sqb += dd * dd; }
            if (k < 3) {
                sn[k][0]=s1a; sn[k][1]=s2a; sn[k][2]=spa; sn[k][3]=sqa;
                sn[k][4]=s1b; sn[k][5]=s2b; sn[k][6]=spb; sn[k][7]=sqb;
            }
            if (k >= 10) {
                const int i = k - 10;
                const int r = 4 * q + i;
                const int sx = r & 7;
                float4 va, vb;
                if (i == 0) {
                    va.x=s1a; va.y=s2a; va.z=spa; va.w=sqa;
                    vb.x=s1b; vb.y=s2b; vb.z=spb; vb.w=sqb;
                } else {
                    va.x=s1a-sn[i-1][0]; va.y=s2a-sn[i-1][1];
                    va.z=spa-sn[i-1][2]; va.w=sqa-sn[i-1][3];
                    vb.x=s1b-sn[i-1][4]; vb.y=s2b-sn[i-1][5];
                    vb.z=spb-sn[i-1][6]; vb.w=sqb-sn[i-1][7];
                }
                cs4[r][(2 * cg)     ^ sx] = va;
                cs4[r][(2 * cg + 1) ^ sx] = vb;
            }
        }
    }
    __syncthreads();

    // ---- Phase 2: horizontal 11-tap sliding window + SSIM ----
    // Output col c (tile-local) uses slots c+1 .. c+11.
    const float w = window[0];
    float ssum = 0.f;
    {
        const int r   = t & 15;
        const int seg = t >> 4;              // 16 segments x 8 cols
        const int c0  = seg * 8;
        const int TWa = min(TW, WW - C0);    // ragged last col-tile (96)
        const int S   = min(8, TWa - c0);
        if (S > 0) {
            const int sx = r & 7;
            float4 win4; win4.x = win4.y = win4.z = win4.w = 0.f;
#pragma unroll
            for (int k = 1; k <= 10; ++k) {
                const float4 v = cs4[r][(c0 + k) ^ sx];
                win4.x += v.x; win4.y += v.y; win4.z += v.z; win4.w += v.w;
            }
            for (int p = 0; p < S; ++p) {
                const float4 v = cs4[r][(c0 + p + 11) ^ sx];
                win4.x += v.x; win4.y += v.y; win4.z += v.z; win4.w += v.w;

                const float mu1  = win4.x * w;
                const float mu2  = win4.y * w;
                const float P    = win4.z * w;   // box((x+y)^2)
                const float Q    = win4.w * w;   // box((x-y)^2)
                const float mu11 = mu1 * mu1;
                const float mu22 = mu2 * mu2;
                const float mu12 = mu1 * mu2;
                const float sigs = 0.5f  * (P + Q) - mu11 - mu22;
                const float s12  = 0.25f * (P - Q) - mu12;
                const float num  = (2.f * mu12 + SSIM_C1) * (2.f * s12 + SSIM_C2);
                const float den  = (mu11 + mu22 + SSIM_C1) * (sigs + SSIM_C2);
                ssum += num / den;

                const float4 o = cs4[r][(c0 + p + 1) ^ sx];
                win4.x -= o.x; win4.y -= o.y; win4.z -= o.z; win4.w -= o.w;
            }
        }
    }

    // ---- Block reduction -> one atomicAdd ----
    float v = ssum;
#pragma unroll
    for (int off = 32; off > 0; off >>= 1) v += __shfl_down(v, off, 64);
    __syncthreads();                          // all LDS reads done; reuse cs4
    float* red = (float*)&cs4[0][0];
    if ((t & 63) == 0) red[t >> 6] = v;
    __syncthreads();
    if (t == 0) atomicAdd(ws, red[0] + red[1] + red[2] + red[3]);
}

__global__ void ssim_fin(const float* __restrict__ ws, float* __restrict__ out, int ntot) {
    out[0] = 1.f - ws[0] / (float)ntot;
}

extern "C" void kernel_launch(void* const* d_in, const int* in_sizes, int n_in,
                              void* d_out, int out_size, void* d_ws, size_t ws_size,
                              hipStream_t stream) {
    const float* img1 = (const float*)d_in[0];
    const float* img2 = (const float*)d_in[1];
    const float* win  = (const float*)d_in[2];
    float* out = (float*)d_out;
    float* ws  = (float*)d_ws;
    const int ntot = in_sizes[0];                       // 32*1024*1024
    const int batches = ntot / (HH * WW);               // 32

    ssim_ws_init<<<dim3(1), dim3(1), 0, stream>>>(ws);
    dim3 grid((WW + TW - 1) / TW, HH / TH, batches);    // 9 x 64 x 32
    ssim_main<<<grid, dim3(256), 0, stream>>>(img1, img2, win, ws);
    ssim_fin<<<dim3(1), dim3(1), 0, stream>>>(ws, out, ntot);
}